// Round 3
// baseline (717.453 us; speedup 1.0000x reference)
//
#include <hip/hip_runtime.h>
#include <cstdint>
#include <cstddef>

#define DEVI __device__ __forceinline__

typedef short bf16x8 __attribute__((ext_vector_type(8)));
typedef short bf16x4 __attribute__((ext_vector_type(4)));
typedef float f32x4  __attribute__((ext_vector_type(4)));

constexpr int H_  = 2048;
constexpr int NH  = 16;
constexpr int NKV = 4;
constexpr int HD  = 128;
constexpr int B_  = 4;
constexpr int QL  = 1024;
constexpr int CL  = 3072;
constexpr int KL  = 4096;   // CL + QL
constexpr float EPS = 1e-6f;
// SCALE * log2(e): folded into stored Q so attention softmax is bare exp2.
// RMSNorm bounds |s| <= sqrt(128)*sqrt(128)*SCALE*log2e = 16.3 -> no-max softmax safe.
constexpr float SCALE_LOG2E = 0.08838834764831845f * 1.4426950408889634f;

DEVI unsigned short f2bf(float x) {
  unsigned int u = __float_as_uint(x);
  u += 0x7FFFu + ((u >> 16) & 1u);   // RNE
  return (unsigned short)(u >> 16);
}
DEVI float bf2f(unsigned short u) {
  return __uint_as_float(((unsigned int)u) << 16);
}
DEVI bf16x4 mk4(float a, float b, float c, float d) {
  unsigned ua = __float_as_uint(a) + 0x8000u, ub = __float_as_uint(b) + 0x8000u;
  unsigned uc = __float_as_uint(c) + 0x8000u, ud = __float_as_uint(d) + 0x8000u;
  union { unsigned u[2]; bf16x4 v; } r;
  r.u[0] = __builtin_amdgcn_perm(ub, ua, 0x07060302u);
  r.u[1] = __builtin_amdgcn_perm(ud, uc, 0x07060302u);
  return r.v;
}

DEVI void async16(const void* g, void* l) {
  __builtin_amdgcn_global_load_lds(
      (const __attribute__((address_space(1))) void*)g,
      (__attribute__((address_space(3))) void*)l, 16, 0, 0);
}

// ---------------------------------------------------------------------------
// prep: kvin_bf[b][pos][h] = bf16(concat(ctx, noise))   (b, KL, H)
// ---------------------------------------------------------------------------
__global__ __launch_bounds__(256)
void prep(const float* __restrict__ noise, const float* __restrict__ ctx,
          unsigned short* __restrict__ kvin) {
  const size_t t = (size_t)blockIdx.x * 256 + threadIdx.x;
  const size_t e = t * 8;
  const int row = (int)(e / H_), col = (int)(e % H_);
  const int b = row >> 12, pos = row & 4095;
  const float* src = (pos < CL) ? ctx + ((size_t)(b * CL + pos)) * H_ + col
                                : noise + ((size_t)(b * QL + (pos - CL))) * H_ + col;
  float4 x = ((const float4*)src)[0], y = ((const float4*)src)[1];
  bf16x8 v;
  v[0] = (short)f2bf(x.x); v[1] = (short)f2bf(x.y);
  v[2] = (short)f2bf(x.z); v[3] = (short)f2bf(x.w);
  v[4] = (short)f2bf(y.x); v[5] = (short)f2bf(y.y);
  v[6] = (short)f2bf(y.z); v[7] = (short)f2bf(y.w);
  *(bf16x8*)(kvin + e) = v;
}

// ---------------------------------------------------------------------------
// Weight transpose + fp32 -> bf16:  in (K x N) fp32  ->  out (N x K) bf16
// ---------------------------------------------------------------------------
__global__ __launch_bounds__(256)
void wtrans(const float* __restrict__ in, unsigned short* __restrict__ out,
            int K, int N) {
  __shared__ float t[64][65];
  const int ktiles = K >> 6;
  const int kt = blockIdx.x % ktiles;
  const int nt = blockIdx.x / ktiles;
  {
    const int r = threadIdx.x >> 2, cs = threadIdx.x & 3;
    const float4* src = (const float4*)(in + (size_t)(kt * 64 + r) * N + nt * 64 + cs * 16);
    #pragma unroll
    for (int i = 0; i < 4; ++i) {
      float4 v = src[i];
      t[r][cs * 16 + i * 4 + 0] = v.x;
      t[r][cs * 16 + i * 4 + 1] = v.y;
      t[r][cs * 16 + i * 4 + 2] = v.z;
      t[r][cs * 16 + i * 4 + 3] = v.w;
    }
  }
  __syncthreads();
  {
    const int n = threadIdx.x >> 2, ks = threadIdx.x & 3;
    bf16x8 o0, o1;
    #pragma unroll
    for (int i = 0; i < 8; ++i) o0[i] = (short)f2bf(t[ks * 16 + i][n]);
    #pragma unroll
    for (int i = 0; i < 8; ++i) o1[i] = (short)f2bf(t[ks * 16 + 8 + i][n]);
    unsigned short* op = out + (size_t)(nt * 64 + n) * K + kt * 64 + ks * 16;
    *(bf16x8*)(op) = o0;
    *(bf16x8*)(op + 8) = o1;
  }
}

// ---------------------------------------------------------------------------
// GEMM, m97-style staging, templated block-M for grid-size scaling.
// MODE 0 (BM=64):  A=kvin rows (b,CL+q) -> rmsnorm+rope*SCALE_LOG2E -> q (b,h,q,d)
// MODE 1 (BM=128): A=kvin, B=WkvT (N=1024): tn<4 -> K rmsnorm+rope (b,kv,p,d)
//                                           tn>=4 -> V transpose (b,kv,d,p)
// MODE 3 (BM=64):  A=attn_out bf16 -> fp32 d_out
// ---------------------------------------------------------------------------
template <int MODE, int BM>
__global__ __launch_bounds__(256)
void gemm3(const unsigned short* __restrict__ Abf,
           const unsigned short* __restrict__ Bt,
           const float* __restrict__ normw,
           const float* __restrict__ cosb, const float* __restrict__ sinb,
           unsigned short* __restrict__ outb, unsigned short* __restrict__ outb2,
           float* __restrict__ outf) {
  constexpr int M  = (MODE == 1) ? (B_ * KL) : (B_ * QL);
  constexpr int K  = H_;
  constexpr int MT = M / BM;
  constexpr int WI = BM / 32;        // i-fragments per wave
  constexpr int AG = BM * 8 / 256;   // A 16B-granules per thread

  __shared__ union {
    struct { unsigned short a[BM][64]; unsigned short b[128][64]; } st;
    unsigned short ct[BM][138];
  } sm;

  const int tid  = threadIdx.x;
  const int tm   = blockIdx.x % MT;
  const int tn   = blockIdx.x / MT;
  const int wid  = tid >> 6, lane = tid & 63, quad = lane >> 4, lm = lane & 15;
  const int wm   = wid >> 1, wn = wid & 1;

  f32x4 acc[WI][4];
  #pragma unroll
  for (int i = 0; i < WI; ++i)
    #pragma unroll
    for (int j = 0; j < 4; ++j)
      #pragma unroll
      for (int r = 0; r < 4; ++r) acc[i][j][r] = 0.f;

  const unsigned short* agp[AG];
  const unsigned short* bgp[4];
  #pragma unroll
  for (int i = 0; i < AG; ++i) {
    const int idx = i * 256 + tid;
    const int arow = idx >> 3, g = idx & 7, gg = g ^ (arow & 7);
    int grow;
    if constexpr (MODE == 0) {
      const int gmr = tm * BM + arow;
      grow = (gmr >> 10) * KL + CL + (gmr & 1023);
    } else {
      grow = tm * BM + arow;
    }
    agp[i] = Abf + (size_t)grow * K + gg * 8;
  }
  #pragma unroll
  for (int i = 0; i < 4; ++i) {
    const int idx = i * 256 + tid;
    const int brow = idx >> 3, g = idx & 7, gg = g ^ (brow & 7);
    bgp[i] = Bt + (size_t)(tn * 128 + brow) * K + gg * 8;
  }

  for (int kt = 0; kt < K / 64; ++kt) {
    __syncthreads();
    #pragma unroll
    for (int i = 0; i < AG; ++i)
      async16(agp[i] + kt * 64, (char*)&sm.st.a[0][0] + (i * 256 + wid * 64) * 16);
    #pragma unroll
    for (int i = 0; i < 4; ++i)
      async16(bgp[i] + kt * 64, (char*)&sm.st.b[0][0] + (i * 256 + wid * 64) * 16);
    __syncthreads();
    #pragma unroll
    for (int ks = 0; ks < 2; ++ks) {
      const int swz = (ks * 4 + quad) ^ (lm & 7);
      bf16x8 af[WI], bfr[4];
      #pragma unroll
      for (int i = 0; i < WI; ++i)
        af[i] = *(const bf16x8*)&sm.st.a[wm * (BM / 2) + i * 16 + lm][swz * 8];
      #pragma unroll
      for (int j = 0; j < 4; ++j)
        bfr[j] = *(const bf16x8*)&sm.st.b[wn * 64 + j * 16 + lm][swz * 8];
      #pragma unroll
      for (int i = 0; i < WI; ++i)
        #pragma unroll
        for (int j = 0; j < 4; ++j)
          acc[i][j] = __builtin_amdgcn_mfma_f32_16x16x32_bf16(af[i], bfr[j], acc[i][j], 0, 0, 0);
    }
  }

  if constexpr (MODE == 3) {
    #pragma unroll
    for (int i = 0; i < WI; ++i)
      #pragma unroll
      for (int j = 0; j < 4; ++j) {
        const int row = tm * BM + wm * (BM / 2) + i * 16 + quad * 4;
        const int col = tn * 128 + wn * 64 + j * 16 + lm;
        #pragma unroll
        for (int rr = 0; rr < 4; ++rr)
          outf[(size_t)(row + rr) * H_ + col] = acc[i][j][rr];
      }
    return;
  }

  // C tile -> LDS bf16
  __syncthreads();
  #pragma unroll
  for (int i = 0; i < WI; ++i)
    #pragma unroll
    for (int j = 0; j < 4; ++j)
      #pragma unroll
      for (int rr = 0; rr < 4; ++rr)
        sm.ct[wm * (BM / 2) + i * 16 + quad * 4 + rr][wn * 64 + j * 16 + lm] =
            f2bf(acc[i][j][rr]);
  __syncthreads();

  if constexpr (MODE == 1) {
    if (tn >= 4) {
      // V^T epilogue: (b, kv, d, pos)
      const int row2 = tid >> 1, half = tid & 1;
      const int d = row2;
      const int b = (tm * 128) >> 12;
      const int posBase = ((tm * 128) & 4095) + half * 64;
      const size_t obase = ((size_t)((b * NKV + (tn - 4)) * HD + d)) * KL + posBase;
      #pragma unroll
      for (int k8 = 0; k8 < 8; ++k8) {
        bf16x8 v;
        #pragma unroll
        for (int j = 0; j < 8; ++j)
          v[j] = (short)sm.ct[half * 64 + k8 * 8 + j][d];
        *(bf16x8*)(outb2 + obase + k8 * 8) = v;
      }
      return;
    }
  }

  // rmsnorm + rope epilogue (MODE 0: Q, MODE 1 tn<4: K)
  {
    constexpr int TPR = 256 / BM;     // threads per row
    constexpr int SEG = 128 / TPR;    // d-span per thread
    const int row2 = tid / TPR, part = tid % TPR;
    const int gmr = tm * BM + row2;
    int ci; size_t obase;
    if constexpr (MODE == 0) {
      const int b = gmr >> 10, pos = gmr & 1023;
      ci = (b * KL + CL + pos) * HD;
      obase = ((size_t)((b * NH + tn) * QL + pos)) * HD;
    } else {
      const int b = gmr >> 12, pos = gmr & 4095;
      ci = (b * KL + pos) * HD;
      obase = ((size_t)((b * NKV + tn) * KL + pos)) * HD;
    }
    float ss = 0.f;
    #pragma unroll
    for (int d8 = 0; d8 < SEG / 8; ++d8) {
      bf16x8 v = *(const bf16x8*)&sm.ct[row2][part * SEG + d8 * 8];
      #pragma unroll
      for (int j = 0; j < 8; ++j) {
        float x = bf2f((unsigned short)v[j]);
        ss += x * x;
      }
    }
    #pragma unroll
    for (int off = 1; off < TPR; off <<= 1) ss += __shfl_xor(ss, off);
    const float rinv = rsqrtf(ss * (1.0f / 128.0f) + EPS);
    constexpr float OSC = (MODE == 0) ? SCALE_LOG2E : 1.0f;
    #pragma unroll
    for (int d8 = 0; d8 < SEG / 8; ++d8) {
      const int dbase = part * SEG + d8 * 8;
      bf16x8 v  = *(const bf16x8*)&sm.ct[row2][dbase];
      bf16x8 mv = *(const bf16x8*)&sm.ct[row2][dbase ^ 64];
      const float4 c0 = *(const float4*)&cosb[ci + dbase];
      const float4 c1 = *(const float4*)&cosb[ci + dbase + 4];
      const float4 s0 = *(const float4*)&sinb[ci + dbase];
      const float4 s1 = *(const float4*)&sinb[ci + dbase + 4];
      const float cs[8] = {c0.x, c0.y, c0.z, c0.w, c1.x, c1.y, c1.z, c1.w};
      const float sn[8] = {s0.x, s0.y, s0.z, s0.w, s1.x, s1.y, s1.z, s1.w};
      bf16x8 ov;
      #pragma unroll
      for (int j = 0; j < 8; ++j) {
        const int d = dbase + j;
        const float x  = bf2f((unsigned short)v[j])  * rinv * normw[d];
        const float xo = bf2f((unsigned short)mv[j]) * rinv * normw[d ^ 64];
        const float rot = (d < 64) ? -xo : xo;
        ov[j] = (short)f2bf((x * cs[j] + rot * sn[j]) * OSC);
      }
      *(bf16x8*)(outb + obase + dbase) = ov;
    }
  }
}

// ---------------------------------------------------------------------------
// Flash attention v3.  Block = (b,h) x 64 q.  Waves split work two ways:
//   QK^T: wave w owns kpos slice [kt*64 + w*16, +16)  (K-frags global->regs)
//   PV:   wave w owns d slice [w*32, +32)             (V^T-frags global->regs)
// Only P transits LDS: written in S^T C-layout (b64), read as 16x16x32
// B-fragments (b128, XOR-swizzled kpos granules).  Each wave's O^T d-slice is
// complete over all kpos -> no cross-wave O reduce; only li (1 KB) reduces.
// No-max softmax in exp2 domain (bounded by RMSNorm).
// ---------------------------------------------------------------------------
__global__ __launch_bounds__(256)
void attn3(const unsigned short* __restrict__ qb,
           const unsigned short* __restrict__ kb,
           const unsigned short* __restrict__ vtb,
           unsigned short* __restrict__ ao) {
  __shared__ unsigned short Pl[64][64];   // 8 KB: P^T [q][kpos], swizzled granules
  __shared__ float liw[4][64];            // per-wave li partials

  const int tid = threadIdx.x;
  const int w = tid >> 6, lane = tid & 63, quad = lane >> 4, lm = lane & 15;
  const int qblk = blockIdx.x & 15;
  const int bh = blockIdx.x >> 4;
  const int b = bh >> 4, h = bh & 15, kvh = h >> 2;
  const int q0 = qblk * 64;

  // Q B-fragments (pre-scaled by SCALE_LOG2E at projection)
  bf16x8 qf[4][4];
  const unsigned short* qbase = qb + ((size_t)((b * NH + h) * QL + q0)) * HD;
  #pragma unroll
  for (int qt = 0; qt < 4; ++qt)
    #pragma unroll
    for (int kq = 0; kq < 4; ++kq)
      qf[qt][kq] = *(const bf16x8*)(qbase + (qt * 16 + lm) * HD + kq * 32 + quad * 8);

  f32x4 o[2][4];
  float liacc[4];
  #pragma unroll
  for (int dt = 0; dt < 2; ++dt)
    #pragma unroll
    for (int qt = 0; qt < 4; ++qt)
      #pragma unroll
      for (int rr = 0; rr < 4; ++rr) o[dt][qt][rr] = 0.f;
  #pragma unroll
  for (int qt = 0; qt < 4; ++qt) liacc[qt] = 0.f;

  const unsigned short* kbase = kb + ((size_t)(b * NKV + kvh)) * KL * HD;
  const unsigned short* vbase = vtb + ((size_t)(b * NKV + kvh)) * HD * KL;

  for (int kt = 0; kt < KL / 64; ++kt) {
    const int ktp = kt * 64;
    // ---- QK^T on own 16-kpos slice (global -> regs) ----
    bf16x8 kf[4];
    const unsigned short* krow = kbase + (size_t)(ktp + w * 16 + lm) * HD;
    #pragma unroll
    for (int kq = 0; kq < 4; ++kq)
      kf[kq] = *(const bf16x8*)(krow + kq * 32 + quad * 8);
    f32x4 s[4];
    #pragma unroll
    for (int qt = 0; qt < 4; ++qt)
      #pragma unroll
      for (int rr = 0; rr < 4; ++rr) s[qt][rr] = 0.f;
    #pragma unroll
    for (int kq = 0; kq < 4; ++kq)
      #pragma unroll
      for (int qt = 0; qt < 4; ++qt)
        s[qt] = __builtin_amdgcn_mfma_f32_16x16x32_bf16(kf[kq], qf[qt][kq], s[qt], 0, 0, 0);

    // exp2 + pack (kpos = ktp + w*16 + quad*4 + rr, q = qt*16 + lm)
    bf16x4 pk[4];
    #pragma unroll
    for (int qt = 0; qt < 4; ++qt) {
      float e0 = __builtin_amdgcn_exp2f(s[qt][0]);
      float e1 = __builtin_amdgcn_exp2f(s[qt][1]);
      float e2 = __builtin_amdgcn_exp2f(s[qt][2]);
      float e3 = __builtin_amdgcn_exp2f(s[qt][3]);
      liacc[qt] += (e0 + e1) + (e2 + e3);
      pk[qt] = mk4(e0, e1, e2, e3);
    }

    __syncthreads();   // prior ktile's PV reads complete
    const int wcol = (((w * 2 + (quad >> 1)) ^ (lm & 7)) << 3) + (quad & 1) * 4;
    #pragma unroll
    for (int qt = 0; qt < 4; ++qt)
      *(bf16x4*)&Pl[qt * 16 + lm][wcol] = pk[qt];
    __syncthreads();   // P visible to all waves

    // ---- PV on own 32-d slice (V^T global -> regs, P from LDS) ----
    #pragma unroll
    for (int ch = 0; ch < 2; ++ch) {
      bf16x8 vf[2];
      #pragma unroll
      for (int dt = 0; dt < 2; ++dt)
        vf[dt] = *(const bf16x8*)(vbase + (size_t)(w * 32 + dt * 16 + lm) * KL +
                                  ktp + ch * 32 + quad * 8);
      #pragma unroll
      for (int qt = 0; qt < 4; ++qt) {
        const int rcol = ((ch * 4 + quad) ^ (lm & 7)) << 3;
        bf16x8 pb = *(const bf16x8*)&Pl[qt * 16 + lm][rcol];
        #pragma unroll
        for (int dt = 0; dt < 2; ++dt)
          o[dt][qt] = __builtin_amdgcn_mfma_f32_16x16x32_bf16(vf[dt], pb, o[dt][qt], 0, 0, 0);
      }
    }
  }

  // li: reduce quads within wave, then across waves via LDS
  #pragma unroll
  for (int qt = 0; qt < 4; ++qt) {
    float v = liacc[qt];
    v += __shfl_xor(v, 16);
    v += __shfl_xor(v, 32);
    if (quad == 0) liw[w][qt * 16 + lm] = v;
  }
  __syncthreads();
  #pragma unroll
  for (int qt = 0; qt < 4; ++qt) {
    const int q = qt * 16 + lm;
    const float l = liw[0][q] + liw[1][q] + liw[2][q] + liw[3][q];
    const float inv = 1.0f / l;
    const size_t rowbase = ((size_t)(b * QL + q0 + q)) * (NH * HD) + h * HD;
    #pragma unroll
    for (int dt = 0; dt < 2; ++dt) {
      bf16x4 vv = mk4(o[dt][qt][0] * inv, o[dt][qt][1] * inv,
                      o[dt][qt][2] * inv, o[dt][qt][3] * inv);
      *(bf16x4*)(ao + rowbase + w * 32 + dt * 16 + quad * 4) = vv;
    }
  }
}

// ---------------------------------------------------------------------------
extern "C" void kernel_launch(void* const* d_in, const int* in_sizes, int n_in,
                              void* d_out, int out_size, void* d_ws, size_t ws_size,
                              hipStream_t stream) {
  const float* noise = (const float*)d_in[0];
  const float* ctx   = (const float*)d_in[1];
  const float* cosb  = (const float*)d_in[2];
  const float* sinb  = (const float*)d_in[3];
  const float* Wq    = (const float*)d_in[4];
  const float* Wk    = (const float*)d_in[5];
  const float* Wv    = (const float*)d_in[6];
  const float* Wo    = (const float*)d_in[7];
  const float* qn    = (const float*)d_in[8];
  const float* kn    = (const float*)d_in[9];
  float* out = (float*)d_out;

  char* ws = (char*)d_ws;
  // kvin [0,64M) dead after projections; aob aliases its head.
  unsigned short* kvin = (unsigned short*)(ws);
  unsigned short* aob  = (unsigned short*)(ws);
  unsigned short* WqT  = (unsigned short*)(ws + 67108864);            //  8 MB
  unsigned short* WkvT = (unsigned short*)(ws + 67108864 + 8388608);  //  4 MB (K heads 0-3, V heads 4-7)
  unsigned short* WoT  = (unsigned short*)(ws + 67108864 + 12582912); //  8 MB
  unsigned short* qbuf = (unsigned short*)(ws + 67108864 + 20971520); // 16 MB
  unsigned short* kbuf = (unsigned short*)(ws + 67108864 + 37748736); // 16 MB
  unsigned short* vtb  = (unsigned short*)(ws + 67108864 + 54525952); // 16 MB (total 132 MB)

  prep<<<dim3((B_ * KL * H_) / 8 / 256), dim3(256), 0, stream>>>(noise, ctx, kvin);

  wtrans<<<dim3(1024), dim3(256), 0, stream>>>(Wq, WqT, 2048, 2048);
  wtrans<<<dim3(256),  dim3(256), 0, stream>>>(Wk, WkvT, 2048, 512);
  wtrans<<<dim3(256),  dim3(256), 0, stream>>>(Wv, WkvT + (size_t)512 * 2048, 2048, 512);
  wtrans<<<dim3(1024), dim3(256), 0, stream>>>(Wo, WoT, 2048, 2048);

  gemm3<0, 64><<<dim3(64 * 16), dim3(256), 0, stream>>>(
      kvin, WqT, qn, cosb, sinb, qbuf, nullptr, nullptr);
  gemm3<1, 128><<<dim3(128 * 8), dim3(256), 0, stream>>>(
      kvin, WkvT, kn, cosb, sinb, kbuf, vtb, nullptr);

  attn3<<<dim3(1024), dim3(256), 0, stream>>>(qbuf, kbuf, vtb, aob);

  gemm3<3, 64><<<dim3(64 * 16), dim3(256), 0, stream>>>(
      aob, WoT, nullptr, nullptr, nullptr, nullptr, nullptr, out);
}

// Round 4
// 644.234 us; speedup vs baseline: 1.1137x; 1.1137x over previous
//
#include <hip/hip_runtime.h>
#include <cstdint>
#include <cstddef>

#define DEVI __device__ __forceinline__

typedef short bf16x8 __attribute__((ext_vector_type(8)));
typedef short bf16x4 __attribute__((ext_vector_type(4)));
typedef float f32x4  __attribute__((ext_vector_type(4)));

constexpr int H_  = 2048;
constexpr int NH  = 16;
constexpr int NKV = 4;
constexpr int HD  = 128;
constexpr int B_  = 4;
constexpr int QL  = 1024;
constexpr int CL  = 3072;
constexpr int KL  = 4096;   // CL + QL
constexpr float EPS = 1e-6f;
// SCALE * log2(e): folded into stored Q so attention softmax is bare exp2.
// RMSNorm bounds |s| <= 16.3 in exp2 domain -> no-max softmax safe in fp32.
constexpr float SCALE_LOG2E = 0.08838834764831845f * 1.4426950408889634f;

DEVI unsigned short f2bf(float x) {
  unsigned int u = __float_as_uint(x);
  u += 0x7FFFu + ((u >> 16) & 1u);   // RNE
  return (unsigned short)(u >> 16);
}
DEVI float bf2f(unsigned short u) {
  return __uint_as_float(((unsigned int)u) << 16);
}
DEVI bf16x4 mk4(float a, float b, float c, float d) {
  unsigned ua = __float_as_uint(a) + 0x8000u, ub = __float_as_uint(b) + 0x8000u;
  unsigned uc = __float_as_uint(c) + 0x8000u, ud = __float_as_uint(d) + 0x8000u;
  union { unsigned u[2]; bf16x4 v; } r;
  r.u[0] = __builtin_amdgcn_perm(ub, ua, 0x07060302u);
  r.u[1] = __builtin_amdgcn_perm(ud, uc, 0x07060302u);
  return r.v;
}

DEVI void async16(const void* g, void* l) {
  __builtin_amdgcn_global_load_lds(
      (const __attribute__((address_space(1))) void*)g,
      (__attribute__((address_space(3))) void*)l, 16, 0, 0);
}

// ---------------------------------------------------------------------------
// prep: kvin_bf[b][pos][h] = bf16(concat(ctx, noise))   (b, KL, H)
// ---------------------------------------------------------------------------
__global__ __launch_bounds__(256)
void prep(const float* __restrict__ noise, const float* __restrict__ ctx,
          unsigned short* __restrict__ kvin) {
  const size_t t = (size_t)blockIdx.x * 256 + threadIdx.x;
  const size_t e = t * 8;
  const int row = (int)(e / H_), col = (int)(e % H_);
  const int b = row >> 12, pos = row & 4095;
  const float* src = (pos < CL) ? ctx + ((size_t)(b * CL + pos)) * H_ + col
                                : noise + ((size_t)(b * QL + (pos - CL))) * H_ + col;
  float4 x = ((const float4*)src)[0], y = ((const float4*)src)[1];
  bf16x8 v;
  v[0] = (short)f2bf(x.x); v[1] = (short)f2bf(x.y);
  v[2] = (short)f2bf(x.z); v[3] = (short)f2bf(x.w);
  v[4] = (short)f2bf(y.x); v[5] = (short)f2bf(y.y);
  v[6] = (short)f2bf(y.z); v[7] = (short)f2bf(y.w);
  *(bf16x8*)(kvin + e) = v;
}

// ---------------------------------------------------------------------------
// Weight transpose + fp32 -> bf16:  in (K x N) fp32  ->  out (N x K) bf16
// ---------------------------------------------------------------------------
__global__ __launch_bounds__(256)
void wtrans(const float* __restrict__ in, unsigned short* __restrict__ out,
            int K, int N) {
  __shared__ float t[64][65];
  const int ktiles = K >> 6;
  const int kt = blockIdx.x % ktiles;
  const int nt = blockIdx.x / ktiles;
  {
    const int r = threadIdx.x >> 2, cs = threadIdx.x & 3;
    const float4* src = (const float4*)(in + (size_t)(kt * 64 + r) * N + nt * 64 + cs * 16);
    #pragma unroll
    for (int i = 0; i < 4; ++i) {
      float4 v = src[i];
      t[r][cs * 16 + i * 4 + 0] = v.x;
      t[r][cs * 16 + i * 4 + 1] = v.y;
      t[r][cs * 16 + i * 4 + 2] = v.z;
      t[r][cs * 16 + i * 4 + 3] = v.w;
    }
  }
  __syncthreads();
  {
    const int n = threadIdx.x >> 2, ks = threadIdx.x & 3;
    bf16x8 o0, o1;
    #pragma unroll
    for (int i = 0; i < 8; ++i) o0[i] = (short)f2bf(t[ks * 16 + i][n]);
    #pragma unroll
    for (int i = 0; i < 8; ++i) o1[i] = (short)f2bf(t[ks * 16 + 8 + i][n]);
    unsigned short* op = out + (size_t)(nt * 64 + n) * K + kt * 64 + ks * 16;
    *(bf16x8*)(op) = o0;
    *(bf16x8*)(op + 8) = o1;
  }
}

// ---------------------------------------------------------------------------
// GEMM, m97-style staging (global_load_lds 16B, XOR granule swizzle).
// MODE 0 (BM=128): A=kvin rows (b,CL+q) -> rmsnorm+rope*SCALE_LOG2E -> q (b,h,q,d)
// MODE 1 (BM=128): A=kvin, B=WkvT (N=1024): tn<4 -> K rmsnorm+rope (b,kv,p,d)
//                                           tn>=4 -> V transpose (b,kv,d,p)
// MODE 3 (BM=128): A=attn_out bf16 -> fp32 d_out
// ---------------------------------------------------------------------------
template <int MODE, int BM>
__global__ __launch_bounds__(256)
void gemm3(const unsigned short* __restrict__ Abf,
           const unsigned short* __restrict__ Bt,
           const float* __restrict__ normw,
           const float* __restrict__ cosb, const float* __restrict__ sinb,
           unsigned short* __restrict__ outb, unsigned short* __restrict__ outb2,
           float* __restrict__ outf) {
  constexpr int M  = (MODE == 1) ? (B_ * KL) : (B_ * QL);
  constexpr int K  = H_;
  constexpr int MT = M / BM;
  constexpr int WI = BM / 32;        // i-fragments per wave
  constexpr int AG = BM * 8 / 256;   // A 16B-granules per thread

  __shared__ union {
    struct { unsigned short a[BM][64]; unsigned short b[128][64]; } st;
    unsigned short ct[BM][138];
  } sm;

  const int tid  = threadIdx.x;
  const int tm   = blockIdx.x % MT;
  const int tn   = blockIdx.x / MT;
  const int wid  = tid >> 6, lane = tid & 63, quad = lane >> 4, lm = lane & 15;
  const int wm   = wid >> 1, wn = wid & 1;

  f32x4 acc[WI][4];
  #pragma unroll
  for (int i = 0; i < WI; ++i)
    #pragma unroll
    for (int j = 0; j < 4; ++j)
      #pragma unroll
      for (int r = 0; r < 4; ++r) acc[i][j][r] = 0.f;

  const unsigned short* agp[AG];
  const unsigned short* bgp[4];
  #pragma unroll
  for (int i = 0; i < AG; ++i) {
    const int idx = i * 256 + tid;
    const int arow = idx >> 3, g = idx & 7, gg = g ^ (arow & 7);
    int grow;
    if constexpr (MODE == 0) {
      const int gmr = tm * BM + arow;
      grow = (gmr >> 10) * KL + CL + (gmr & 1023);
    } else {
      grow = tm * BM + arow;
    }
    agp[i] = Abf + (size_t)grow * K + gg * 8;
  }
  #pragma unroll
  for (int i = 0; i < 4; ++i) {
    const int idx = i * 256 + tid;
    const int brow = idx >> 3, g = idx & 7, gg = g ^ (brow & 7);
    bgp[i] = Bt + (size_t)(tn * 128 + brow) * K + gg * 8;
  }

  for (int kt = 0; kt < K / 64; ++kt) {
    __syncthreads();
    #pragma unroll
    for (int i = 0; i < AG; ++i)
      async16(agp[i] + kt * 64, (char*)&sm.st.a[0][0] + (i * 256 + wid * 64) * 16);
    #pragma unroll
    for (int i = 0; i < 4; ++i)
      async16(bgp[i] + kt * 64, (char*)&sm.st.b[0][0] + (i * 256 + wid * 64) * 16);
    __syncthreads();
    #pragma unroll
    for (int ks = 0; ks < 2; ++ks) {
      const int swz = (ks * 4 + quad) ^ (lm & 7);
      bf16x8 af[WI], bfr[4];
      #pragma unroll
      for (int i = 0; i < WI; ++i)
        af[i] = *(const bf16x8*)&sm.st.a[wm * (BM / 2) + i * 16 + lm][swz * 8];
      #pragma unroll
      for (int j = 0; j < 4; ++j)
        bfr[j] = *(const bf16x8*)&sm.st.b[wn * 64 + j * 16 + lm][swz * 8];
      #pragma unroll
      for (int i = 0; i < WI; ++i)
        #pragma unroll
        for (int j = 0; j < 4; ++j)
          acc[i][j] = __builtin_amdgcn_mfma_f32_16x16x32_bf16(af[i], bfr[j], acc[i][j], 0, 0, 0);
    }
  }

  if constexpr (MODE == 3) {
    #pragma unroll
    for (int i = 0; i < WI; ++i)
      #pragma unroll
      for (int j = 0; j < 4; ++j) {
        const int row = tm * BM + wm * (BM / 2) + i * 16 + quad * 4;
        const int col = tn * 128 + wn * 64 + j * 16 + lm;
        #pragma unroll
        for (int rr = 0; rr < 4; ++rr)
          outf[(size_t)(row + rr) * H_ + col] = acc[i][j][rr];
      }
    return;
  }

  // C tile -> LDS bf16
  __syncthreads();
  #pragma unroll
  for (int i = 0; i < WI; ++i)
    #pragma unroll
    for (int j = 0; j < 4; ++j)
      #pragma unroll
      for (int rr = 0; rr < 4; ++rr)
        sm.ct[wm * (BM / 2) + i * 16 + quad * 4 + rr][wn * 64 + j * 16 + lm] =
            f2bf(acc[i][j][rr]);
  __syncthreads();

  if constexpr (MODE == 1) {
    if (tn >= 4) {
      // V^T epilogue: (b, kv, d, pos)
      const int row2 = tid >> 1, half = tid & 1;
      const int d = row2;
      const int b = (tm * 128) >> 12;
      const int posBase = ((tm * 128) & 4095) + half * 64;
      const size_t obase = ((size_t)((b * NKV + (tn - 4)) * HD + d)) * KL + posBase;
      #pragma unroll
      for (int k8 = 0; k8 < 8; ++k8) {
        bf16x8 v;
        #pragma unroll
        for (int j = 0; j < 8; ++j)
          v[j] = (short)sm.ct[half * 64 + k8 * 8 + j][d];
        *(bf16x8*)(outb2 + obase + k8 * 8) = v;
      }
      return;
    }
  }

  // rmsnorm + rope epilogue (MODE 0: Q, MODE 1 tn<4: K)
  {
    constexpr int TPR = 256 / BM;     // threads per row
    constexpr int SEG = 128 / TPR;    // d-span per thread
    const int row2 = tid / TPR, part = tid % TPR;
    const int gmr = tm * BM + row2;
    int ci; size_t obase;
    if constexpr (MODE == 0) {
      const int b = gmr >> 10, pos = gmr & 1023;
      ci = (b * KL + CL + pos) * HD;
      obase = ((size_t)((b * NH + tn) * QL + pos)) * HD;
    } else {
      const int b = gmr >> 12, pos = gmr & 4095;
      ci = (b * KL + pos) * HD;
      obase = ((size_t)((b * NKV + tn) * KL + pos)) * HD;
    }
    float ss = 0.f;
    #pragma unroll
    for (int d8 = 0; d8 < SEG / 8; ++d8) {
      bf16x8 v = *(const bf16x8*)&sm.ct[row2][part * SEG + d8 * 8];
      #pragma unroll
      for (int j = 0; j < 8; ++j) {
        float x = bf2f((unsigned short)v[j]);
        ss += x * x;
      }
    }
    #pragma unroll
    for (int off = 1; off < TPR; off <<= 1) ss += __shfl_xor(ss, off);
    const float rinv = rsqrtf(ss * (1.0f / 128.0f) + EPS);
    constexpr float OSC = (MODE == 0) ? SCALE_LOG2E : 1.0f;
    #pragma unroll
    for (int d8 = 0; d8 < SEG / 8; ++d8) {
      const int dbase = part * SEG + d8 * 8;
      bf16x8 v  = *(const bf16x8*)&sm.ct[row2][dbase];
      bf16x8 mv = *(const bf16x8*)&sm.ct[row2][dbase ^ 64];
      const float4 c0 = *(const float4*)&cosb[ci + dbase];
      const float4 c1 = *(const float4*)&cosb[ci + dbase + 4];
      const float4 s0 = *(const float4*)&sinb[ci + dbase];
      const float4 s1 = *(const float4*)&sinb[ci + dbase + 4];
      const float cs[8] = {c0.x, c0.y, c0.z, c0.w, c1.x, c1.y, c1.z, c1.w};
      const float sn[8] = {s0.x, s0.y, s0.z, s0.w, s1.x, s1.y, s1.z, s1.w};
      bf16x8 ov;
      #pragma unroll
      for (int j = 0; j < 8; ++j) {
        const int d = dbase + j;
        const float x  = bf2f((unsigned short)v[j])  * rinv * normw[d];
        const float xo = bf2f((unsigned short)mv[j]) * rinv * normw[d ^ 64];
        const float rot = (d < 64) ? -xo : xo;
        ov[j] = (short)f2bf((x * cs[j] + rot * sn[j]) * OSC);
      }
      *(bf16x8*)(outb + obase + dbase) = ov;
    }
  }
}

// ---------------------------------------------------------------------------
// Flash attention v4.  Block = (b,h) x 64 q rows; waves split by KPOS:
// wave w owns kpos slice [kt*64 + w*16, +16).  K/V tiles staged via
// global_load_lds (XOR granule swizzle); each K/V byte read from LDS ONCE.
// S^T = K Q^T (16x16x32); its C-layout (k=quad*4+rr, n=lm) IS the x16
// B-operand layout, so P = exp2(S^T) feeds PV (O^T += V^T P^T, 16x16x16)
// straight from registers.  Per-wave partial O^T reduced via LDS at end.
// XCD-affinity blockIdx mapping keeps each (b,kvh)'s 2 MB K/V hot in one
// XCD's 4 MB L2.
// ---------------------------------------------------------------------------
__global__ __launch_bounds__(256, 2)
void attn4(const unsigned short* __restrict__ qb,
           const unsigned short* __restrict__ kb,
           const unsigned short* __restrict__ vtb,
           unsigned short* __restrict__ ao) {
  __shared__ union {
    struct { unsigned short kl[64][128]; unsigned short vl[128][64]; } t; // 32 KB
    float red[4][2][4][16][17];                                           // 34.8 KB
  } sm;
  __shared__ float liw[4][64];

  const int tid = threadIdx.x;
  const int w = tid >> 6, lane = tid & 63, quad = lane >> 4, lm = lane & 15;

  // XCD-affinity mapping: xcd = blockIdx&7 (hw round-robin assumption; perf-only)
  const int xcd = blockIdx.x & 7;
  const int idx = blockIdx.x >> 3;          // 0..127
  const int g   = xcd + 8 * (idx & 1);      // (b,kvh) group 0..15
  const int j   = idx >> 1;                 // 0..63
  const int qblk = j & 15, hsub = j >> 4;
  const int b = g >> 2, kvh = g & 3, h = kvh * 4 + hsub;
  const int q0 = qblk * 64;

  // Q B-fragments, resident (pre-scaled by SCALE_LOG2E at projection)
  bf16x8 qf[4][4];
  const unsigned short* qbase = qb + ((size_t)((b * NH + h) * QL + q0)) * HD;
  #pragma unroll
  for (int qt = 0; qt < 4; ++qt)
    #pragma unroll
    for (int kq = 0; kq < 4; ++kq)
      qf[qt][kq] = *(const bf16x8*)(qbase + (qt * 16 + lm) * HD + kq * 32 + quad * 8);

  f32x4 o[8][4];       // O^T partial: d = dt*16 + quad*4 + rr, q = qt*16 + lm
  float liacc[4];
  #pragma unroll
  for (int dt = 0; dt < 8; ++dt)
    #pragma unroll
    for (int qt = 0; qt < 4; ++qt)
      #pragma unroll
      for (int rr = 0; rr < 4; ++rr) o[dt][qt][rr] = 0.f;
  #pragma unroll
  for (int qt = 0; qt < 4; ++qt) liacc[qt] = 0.f;

  const unsigned short* kbase = kb + ((size_t)(b * NKV + kvh)) * KL * HD;
  const unsigned short* vbase = vtb + ((size_t)(b * NKV + kvh)) * HD * KL;

  // staging pointers (i=0 granule; i>0 = fixed strides, row&7 invariant)
  const int sidx = w * 64 + lane;           // 0..255
  const int kr0 = sidx >> 4, kgc = sidx & 15;
  const int kgg = (kgc & 8) | ((kgc & 7) ^ (kr0 & 7));
  const unsigned short* kgp0 = kbase + (size_t)kr0 * HD + kgg * 8;
  const int vr0 = sidx >> 3, vg = sidx & 7;
  const int vgg = vg ^ (vr0 & 7);
  const unsigned short* vgp0 = vbase + (size_t)vr0 * KL + vgg * 8;

  for (int kt = 0; kt < KL / 64; ++kt) {
    const int ktp = kt * 64;
    __syncthreads();
    #pragma unroll
    for (int i = 0; i < 4; ++i) {
      async16(kgp0 + (size_t)ktp * HD + i * (16 * HD),
              (char*)&sm.t.kl[0][0] + (i * 256 + w * 64) * 16);
      async16(vgp0 + (size_t)i * (32 * KL) + ktp,
              (char*)&sm.t.vl[0][0] + (i * 256 + w * 64) * 16);
    }
    __syncthreads();

    // ---- S^T = K_slice · Q^T  (wave's 16 kpos x 64 q) ----
    f32x4 s[4];
    #pragma unroll
    for (int qt = 0; qt < 4; ++qt)
      #pragma unroll
      for (int rr = 0; rr < 4; ++rr) s[qt][rr] = 0.f;
    #pragma unroll
    for (int kq = 0; kq < 4; ++kq) {
      const int gH = kq * 4 + quad;
      const int col = (gH & 8) | ((gH & 7) ^ (lm & 7));
      bf16x8 kf = *(const bf16x8*)&sm.t.kl[w * 16 + lm][col * 8];
      #pragma unroll
      for (int qt = 0; qt < 4; ++qt)
        s[qt] = __builtin_amdgcn_mfma_f32_16x16x32_bf16(kf, qf[qt][kq], s[qt], 0, 0, 0);
    }

    // ---- p = exp2(s) in regs; C-layout == x16 B-operand layout ----
    bf16x4 pk[4];
    #pragma unroll
    for (int qt = 0; qt < 4; ++qt) {
      float e0 = __builtin_amdgcn_exp2f(s[qt][0]);
      float e1 = __builtin_amdgcn_exp2f(s[qt][1]);
      float e2 = __builtin_amdgcn_exp2f(s[qt][2]);
      float e3 = __builtin_amdgcn_exp2f(s[qt][3]);
      liacc[qt] += (e0 + e1) + (e2 + e3);
      pk[qt] = mk4(e0, e1, e2, e3);
    }

    // ---- O^T += V^T_slice · P^T  (x16, K = wave's 16 kpos) ----
    const int gvi = (w * 2 + (quad >> 1)) ^ (lm & 7);
    const int voff = gvi * 8 + (quad & 1) * 4;
    #pragma unroll
    for (int dt = 0; dt < 8; ++dt) {
      bf16x4 vf = *(const bf16x4*)&sm.t.vl[dt * 16 + lm][voff];
      #pragma unroll
      for (int qt = 0; qt < 4; ++qt)
        o[dt][qt] = __builtin_amdgcn_mfma_f32_16x16x16bf16_1k(vf, pk[qt], o[dt][qt], 0, 0, 0);
    }
  }

  // ---- li: quad-reduce in wave, publish per-wave partials ----
  #pragma unroll
  for (int qt = 0; qt < 4; ++qt) {
    float v = liacc[qt];
    v += __shfl_xor(v, 16);
    v += __shfl_xor(v, 32);
    if (quad == 0) liw[w][qt * 16 + lm] = v;
  }
  __syncthreads();

  // ---- cross-wave O reduction through LDS, 4 chunks of 2 d-tiles ----
  const int qc = tid >> 2;                 // 0..63
  const int qt_o = qc >> 4, c16 = qc & 15;
  const int dtc_o = (tid & 2) >> 1, rh = (tid & 1) * 8;
  const int q_o = qt_o * 16 + c16;
  const float inv =
      1.0f / (liw[0][q_o] + liw[1][q_o] + liw[2][q_o] + liw[3][q_o]);
  unsigned short* obase =
      ao + ((size_t)(b * QL + q0 + q_o)) * (NH * HD) + h * HD;

  #pragma unroll
  for (int chunk = 0; chunk < 4; ++chunk) {
    __syncthreads();   // prior chunk reads (and final PV kl/vl reads) done
    #pragma unroll
    for (int dtc = 0; dtc < 2; ++dtc)
      #pragma unroll
      for (int qt = 0; qt < 4; ++qt)
        #pragma unroll
        for (int rr = 0; rr < 4; ++rr)
          sm.red[w][dtc][qt][quad * 4 + rr][lm] = o[chunk * 2 + dtc][qt][rr];
    __syncthreads();
    bf16x8 ov;
    #pragma unroll
    for (int i = 0; i < 8; ++i) {
      const int r = rh + i;
      const float v = (sm.red[0][dtc_o][qt_o][r][c16] +
                       sm.red[1][dtc_o][qt_o][r][c16] +
                       sm.red[2][dtc_o][qt_o][r][c16] +
                       sm.red[3][dtc_o][qt_o][r][c16]) * inv;
      ov[i] = (short)f2bf(v);
    }
    *(bf16x8*)(obase + (chunk * 2 + dtc_o) * 16 + rh) = ov;
  }
}

// ---------------------------------------------------------------------------
extern "C" void kernel_launch(void* const* d_in, const int* in_sizes, int n_in,
                              void* d_out, int out_size, void* d_ws, size_t ws_size,
                              hipStream_t stream) {
  const float* noise = (const float*)d_in[0];
  const float* ctx   = (const float*)d_in[1];
  const float* cosb  = (const float*)d_in[2];
  const float* sinb  = (const float*)d_in[3];
  const float* Wq    = (const float*)d_in[4];
  const float* Wk    = (const float*)d_in[5];
  const float* Wv    = (const float*)d_in[6];
  const float* Wo    = (const float*)d_in[7];
  const float* qn    = (const float*)d_in[8];
  const float* kn    = (const float*)d_in[9];
  float* out = (float*)d_out;

  char* ws = (char*)d_ws;
  // kvin [0,64M) dead after projections; aob aliases its head.
  unsigned short* kvin = (unsigned short*)(ws);
  unsigned short* aob  = (unsigned short*)(ws);
  unsigned short* WqT  = (unsigned short*)(ws + 67108864);            //  8 MB
  unsigned short* WkvT = (unsigned short*)(ws + 67108864 + 8388608);  //  4 MB
  unsigned short* WoT  = (unsigned short*)(ws + 67108864 + 12582912); //  8 MB
  unsigned short* qbuf = (unsigned short*)(ws + 67108864 + 20971520); // 16 MB
  unsigned short* kbuf = (unsigned short*)(ws + 67108864 + 37748736); // 16 MB
  unsigned short* vtb  = (unsigned short*)(ws + 67108864 + 54525952); // 16 MB

  prep<<<dim3((B_ * KL * H_) / 8 / 256), dim3(256), 0, stream>>>(noise, ctx, kvin);

  wtrans<<<dim3(1024), dim3(256), 0, stream>>>(Wq, WqT, 2048, 2048);
  wtrans<<<dim3(256),  dim3(256), 0, stream>>>(Wk, WkvT, 2048, 512);
  wtrans<<<dim3(256),  dim3(256), 0, stream>>>(Wv, WkvT + (size_t)512 * 2048, 2048, 512);
  wtrans<<<dim3(1024), dim3(256), 0, stream>>>(Wo, WoT, 2048, 2048);

  gemm3<0, 128><<<dim3(32 * 16), dim3(256), 0, stream>>>(
      kvin, WqT, qn, cosb, sinb, qbuf, nullptr, nullptr);
  gemm3<1, 128><<<dim3(128 * 8), dim3(256), 0, stream>>>(
      kvin, WkvT, kn, cosb, sinb, kbuf, vtb, nullptr);

  attn4<<<dim3(1024), dim3(256), 0, stream>>>(qbuf, kbuf, vtb, aob);

  gemm3<3, 128><<<dim3(32 * 16), dim3(256), 0, stream>>>(
      aob, WoT, nullptr, nullptr, nullptr, nullptr, nullptr, out);
}